// Round 9
// baseline (25.397 us; speedup 1.0000x reference)
//
#include <hip/hip_runtime.h>

#define NS 128
#define NX 512
#define NY 512
#define NT 2048

// ===== NUMERICS CONTRACT (R2/R4 failed; R0/R3/R5-R8 passed) =====
// floor(idx) must match the np reference everywhere; idx recipe:
//     dist = CORRECTLY-ROUNDED sqrt(dx*dx + dy*dy);   // RN, unique
//     idx  = dist * (1.0f/1500.0f) * (1.0f/4e-08f);   // two separate muls
// sqrt_cr below (LLVM lowerFSQRTF32 Tuckerman core, guards stripped) proven
// bit-exact in R7/R8 (absmax 0.0625). fract proven safe (affects only w0).
// Forbidden: folded scale inside sqrt (R2), raw 1-ulp v_sqrt for idx (R2),
// packed float2 geometry (R4 — breaks the fma contraction of d2), changing
// the d2 expression text. Accumulation FORM is free (tolerance 0.895).

__device__ __forceinline__ float sqrt_cr(float x) {
    const float r0 = __builtin_amdgcn_sqrtf(x);               // <=1 ulp
    const float rd = __int_as_float(__float_as_int(r0) - 1);  // r0 - 1ulp
    const float ru = __int_as_float(__float_as_int(r0) + 1);  // r0 + 1ulp
    const float vd = fmaf(-rd, r0, x);
    const float vu = fmaf(-ru, r0, x);
    float r = (vd <= 0.0f) ? rd : r0;
    r = (vu > 0.0f) ? ru : r;
    return r;
}

// 4 pixels per lane (j, j+8, j+16, j+24): four independent frozen-DAG
// chains -> 8 gathers in flight per unrolled body, 4-way sqrt interleave.
__global__ __launch_bounds__(256) void das_kernel(
        const float* __restrict__ x,        // (NS, NT)
        const float* __restrict__ sensors,  // (NS, 2)
        const float* __restrict__ grid,     // (P, 2)
        float* __restrict__ out) {          // (P,)
    const int tid = threadIdx.x;
    const int lane = tid & 63;
    const int wave = tid >> 6;              // 0..3 = sensor quarter

    // 8x32-pixel tile per block; lane covers (i, j+8c), c=0..3
    const int tileIdx = blockIdx.x;         // 1024 tiles
    const int ti = tileIdx >> 4;            // 0..63
    const int tjj = tileIdx & 15;           // 0..15
    const int i = ti * 8 + (lane >> 3);
    const int j = tjj * 32 + (lane & 7);
    const int p0 = i * NY + j;

    const float2 g0 = reinterpret_cast<const float2*>(grid)[p0];
    const float2 g1 = reinterpret_cast<const float2*>(grid)[p0 + 8];
    const float2 g2 = reinterpret_cast<const float2*>(grid)[p0 + 16];
    const float2 g3 = reinterpret_cast<const float2*>(grid)[p0 + 24];

    const float inv_c = 1.0f / 1500.0f;
    const float inv_dt = 1.0f / 4e-08f;

    // wave-uniform sensor base; full unroll hoists sensor s_loads
    const int sbase = __builtin_amdgcn_readfirstlane(wave << 5);
    const float2* svp = reinterpret_cast<const float2*>(sensors) + sbase;
    const float* xrow0 = x + sbase * NT;

    float accA0 = 0.0f, accB0 = 0.0f, accA1 = 0.0f, accB1 = 0.0f;
    float accA2 = 0.0f, accB2 = 0.0f, accA3 = 0.0f, accB3 = 0.0f;
#pragma unroll
    for (int s = 0; s < 32; ++s) {
        const float2 sv = svp[s];                      // uniform -> s_load
        const float* row = xrow0 + s * NT;             // SGPR base

        const float dx0 = g0.x - sv.x;
        const float dy0 = g0.y - sv.y;
        const float idx0 = sqrt_cr(dx0 * dx0 + dy0 * dy0) * inv_c * inv_dt;
        const float dx1 = g1.x - sv.x;
        const float dy1 = g1.y - sv.y;
        const float idx1 = sqrt_cr(dx1 * dx1 + dy1 * dy1) * inv_c * inv_dt;
        const float dx2 = g2.x - sv.x;
        const float dy2 = g2.y - sv.y;
        const float idx2 = sqrt_cr(dx2 * dx2 + dy2 * dy2) * inv_c * inv_dt;
        const float dx3 = g3.x - sv.x;
        const float dy3 = g3.y - sv.y;
        const float idx3 = sqrt_cr(dx3 * dx3 + dy3 * dy3) * inv_c * inv_dt;

        const int i00 = (int)idx0;                     // trunc == floor
        const int i10 = (int)idx1;
        const int i20 = (int)idx2;
        const int i30 = (int)idx3;
        const float w00 = __builtin_amdgcn_fractf(idx0);
        const float w10 = __builtin_amdgcn_fractf(idx1);
        const float w20 = __builtin_amdgcn_fractf(idx2);
        const float w30 = __builtin_amdgcn_fractf(idx3);

        const float y00 = row[i00];
        const float y01 = row[i00 + 1];
        const float y10 = row[i10];
        const float y11 = row[i10 + 1];
        const float y20 = row[i20];
        const float y21 = row[i20 + 1];
        const float y30 = row[i30];
        const float y31 = row[i30 + 1];

        accA0 = fmaf(w00, y00 - y01, accA0);  accB0 += y01;
        accA1 = fmaf(w10, y10 - y11, accA1);  accB1 += y11;
        accA2 = fmaf(w20, y20 - y21, accA2);  accB2 += y21;
        accA3 = fmaf(w30, y30 - y31, accA3);  accB3 += y31;
    }

    __shared__ float part[4][256];
    part[0][tid] = accA0 + accB0;
    part[1][tid] = accA1 + accB1;
    part[2][tid] = accA2 + accB2;
    part[3][tid] = accA3 + accB3;
    __syncthreads();
    // wave w reduces pixel-set w across the 4 sensor quarters
    const int c = wave;
    const int rl = lane;
    const int ri = ti * 8 + (rl >> 3);
    const int rj = tjj * 32 + (rl & 7) + 8 * c;
    out[ri * NY + rj] = part[c][rl] + part[c][rl + 64] + part[c][rl + 128] + part[c][rl + 192];
}

extern "C" void kernel_launch(void* const* d_in, const int* in_sizes, int n_in,
                              void* d_out, int out_size, void* d_ws, size_t ws_size,
                              hipStream_t stream) {
    const float* x = (const float*)d_in[0];        // (1, NS, NT)
    const float* sensors = (const float*)d_in[1];  // (NS, 2)
    const float* grid = (const float*)d_in[2];     // (P, 2)
    float* out = (float*)d_out;                    // (1, NX, NY)

    const int nTiles = (NX / 8) * (NY / 32);       // 1024 blocks, 4 waves each
    das_kernel<<<nTiles, 256, 0, stream>>>(x, sensors, grid, out);
}

// Round 11
// 24.402 us; speedup vs baseline: 1.0408x; 1.0408x over previous
//
#include <hip/hip_runtime.h>

#define NS 128
#define NX 512
#define NY 512
#define NT 2048
#define WIN 32          // per-sensor LDS window (pow2 -> div-free staging)
#define TI 16           // tile rows (i)
#define TJ 8            // tile cols (j)

// ===== NUMERICS CONTRACT (R2/R4/R10 failed; R0/R3/R5-R9 passed) =====
// floor(idx) must match the np reference everywhere; idx recipe:
//     dist = CORRECTLY-ROUNDED sqrt(dx*dx + dy*dy);   // RN, unique
//     idx  = dist * (1.0f/1500.0f) * (1.0f/4e-08f);   // two separate muls
// sqrt_cr (LLVM lowerFSQRTF32 Tuckerman core, guards stripped) proven
// bit-exact R7-R9 (absmax 0.0625). fract proven safe (only affects w0).
// Forbidden: folded scale inside sqrt (R2), raw v_sqrt for idx (R2),
// packed float2 geometry (R4), changing the d2 expression text.
// R10's failure was NOT numerics: the window staging read row 0 for all
// sensors (missing s*NT). Fixed via explicit per-sensor global base.
// Coverage proof: |idx(pixel) - idx(ref(7,3))| <= 11.7 samples (triangle
// ineq, tile diag), window slot e = i0 - ws in [3, 28] ⊂ [0,31), e+1 <= 29.

__device__ __forceinline__ float sqrt_cr(float x) {
    const float r0 = __builtin_amdgcn_sqrtf(x);               // <=1 ulp
    const float rd = __int_as_float(__float_as_int(r0) - 1);
    const float ru = __int_as_float(__float_as_int(r0) + 1);
    const float vd = fmaf(-rd, r0, x);
    const float vu = fmaf(-ru, r0, x);
    float r = (vd <= 0.0f) ? rd : r0;
    r = (vu > 0.0f) ? ru : r;
    return r;
}

__global__ __launch_bounds__(512, 8) void das_kernel(
        const float* __restrict__ x,        // (NS, NT)
        const float* __restrict__ sensors,  // (NS, 2)
        const float* __restrict__ grid,     // (P, 2)
        float* __restrict__ out) {          // (P,)
    __shared__ float win[NS * WIN];         // 16 KB sample windows
    __shared__ int ldsoff[NS];              // s*WIN - ws[s]   (main-loop addr)
    __shared__ int gbase[NS];               // s*NT  + ws[s]   (staging addr)
    __shared__ float part[512];

    const int tid = threadIdx.x;
    const int bi = blockIdx.x;              // 2048 blocks
    const int ti = bi >> 6;                 // 0..31  (NX/TI)
    const int tj = bi & 63;                 // 0..63  (NY/TJ)

    // --- phase 1: per-sensor window base from tile reference pixel (7,3).
    // Raw v_sqrt OK here: only selects the staged window (slack >= 3).
    if (tid < NS) {
        const float2 sv = reinterpret_cast<const float2*>(sensors)[tid];
        const float2 gc = reinterpret_cast<const float2*>(
            grid)[(ti * TI + 7) * NY + (tj * TJ + 3)];
        const float dx = gc.x - sv.x;
        const float dy = gc.y - sv.y;
        const float idxc = __builtin_amdgcn_sqrtf(dx * dx + dy * dy)
                           * (1.0f / 1500.0f) * (1.0f / 4e-08f);
        const int ws = (int)idxc - 15;      // window covers ws .. ws+31
        ldsoff[tid] = tid * WIN - ws;
        gbase[tid]  = tid * NT + ws;        // THE R10 FIX: row base included
    }
    __syncthreads();

    // --- phase 2: stage windows.  win[s*32+e] = x[s*NT + ws[s] + e]
#pragma unroll
    for (int r = 0; r < (NS * WIN) / 512; ++r) {
        const int k = r * 512 + tid;
        win[k] = x[gbase[k >> 5] + (k & 31)];
    }
    __syncthreads();

    // --- main loop: 1 pixel per thread, 32 sensors per thread (4-way split)
    const int pl = tid & 127;               // pixel in 16x8 tile
    const int quad = tid >> 7;              // sensor quarter
    const int i = ti * TI + (pl >> 3);
    const int j = tj * TJ + (pl & 7);
    const int p = i * NY + j;
    const float2 g = reinterpret_cast<const float2*>(grid)[p];

    const float inv_c = 1.0f / 1500.0f;
    const float inv_dt = 1.0f / 4e-08f;
    const int sbase = __builtin_amdgcn_readfirstlane(quad << 5);
    const float2* svp = reinterpret_cast<const float2*>(sensors) + sbase;

    float accA = 0.0f, accB = 0.0f;
#pragma unroll
    for (int s4 = 0; s4 < 8; ++s4) {
        const int4 off4 = *reinterpret_cast<const int4*>(&ldsoff[sbase + s4 * 4]);
#pragma unroll
        for (int u = 0; u < 4; ++u) {
            const int s = s4 * 4 + u;
            const float2 sv = svp[s];                  // uniform -> s_load
            const float dx = g.x - sv.x;
            const float dy = g.y - sv.y;
            const float idx = sqrt_cr(dx * dx + dy * dy) * inv_c * inv_dt; // FROZEN
            const int i0 = (int)idx;                   // trunc == floor
            const float w0 = __builtin_amdgcn_fractf(idx);
            const int o = (u == 0) ? off4.x : (u == 1) ? off4.y
                        : (u == 2) ? off4.z : off4.w;  // static select (unrolled)
            const float* wp = &win[i0 + o];            // = &x[s*NT + i0] staged
            const float y0 = wp[0];                    // ds_read2_b32
            const float y1 = wp[1];
            accA = fmaf(w0, y0 - y1, accA);            // y1 + w0*(y0-y1)
            accB += y1;
        }
    }
    part[tid] = accA + accB;
    __syncthreads();
    if (tid < 128)
        out[p] = part[tid] + part[tid + 128] + part[tid + 256] + part[tid + 384];
}

extern "C" void kernel_launch(void* const* d_in, const int* in_sizes, int n_in,
                              void* d_out, int out_size, void* d_ws, size_t ws_size,
                              hipStream_t stream) {
    const float* x = (const float*)d_in[0];        // (1, NS, NT)
    const float* sensors = (const float*)d_in[1];  // (NS, 2)
    const float* grid = (const float*)d_in[2];     // (P, 2)
    float* out = (float*)d_out;                    // (1, NX, NY)

    const int nblocks = (NX / TI) * (NY / TJ);     // 2048 blocks, 512 threads
    das_kernel<<<nblocks, 512, 0, stream>>>(x, sensors, grid, out);
}